// Round 1
// baseline (476.697 us; speedup 1.0000x reference)
//
#include <hip/hip_runtime.h>
#include <cfloat>

#ifndef __has_builtin
#define __has_builtin(x) 0
#endif

__device__ __forceinline__ float fexp2(float x) {
#if __has_builtin(__builtin_amdgcn_exp2f)
    return __builtin_amdgcn_exp2f(x);   // v_exp_f32
#else
    return exp2f(x);
#endif
}
__device__ __forceinline__ float flog2(float x) {
#if __has_builtin(__builtin_amdgcn_logf)
    return __builtin_amdgcn_logf(x);    // v_log_f32
#else
    return log2f(x);
#endif
}

#define NITERS 21

// One 256-thread block per 128x128 matrix.
// Thread t owns an 8x8 sub-tile: rows rg*8..rg*8+7 (rg = t>>4), cols cg*8..cg*8+7 (cg = t&15).
// Matrix kept scaled in registers as x = input * (1/T)*log2(e); current state is
// implicitly  la = x - r_i - c_j  (base-2 logs). Each phase replaces r (or c) with
// its base-2 logsumexp, shifted by the previous offset for stability.
__global__ __launch_bounds__(256) void sinkhorn_kernel(const float* __restrict__ in,
                                                       float* __restrict__ out) {
    const int t  = threadIdx.x;
    const int rg = t >> 4;     // 0..15
    const int cg = t & 15;     // 0..15
    const int wv = t >> 6;     // wave 0..3
    const size_t base = (size_t)blockIdx.x * (128 * 128);
    const float* __restrict__ src = in  + base + (size_t)(rg << 10) + (cg << 3);
    float*       __restrict__ dst = out + base + (size_t)(rg << 10) + (cg << 3);

    const float SCALE = 36.067376022224085f;  // (1/0.04) * log2(e)

    float x[8][8];
#pragma unroll
    for (int i = 0; i < 8; ++i) {
        float4 a = *(const float4*)(src + i * 128);
        float4 b = *(const float4*)(src + i * 128 + 4);
        x[i][0] = a.x * SCALE; x[i][1] = a.y * SCALE;
        x[i][2] = a.z * SCALE; x[i][3] = a.w * SCALE;
        x[i][4] = b.x * SCALE; x[i][5] = b.y * SCALE;
        x[i][6] = b.z * SCALE; x[i][7] = b.w * SCALE;
    }

    __shared__ float lds[4][128];

    float r[8], c[8];
#pragma unroll
    for (int j = 0; j < 8; ++j) c[j] = 0.0f;

    // ---- iteration 1 row phase: true max stabilization (c == 0) ----
#pragma unroll
    for (int i = 0; i < 8; ++i) {
        float m = x[i][0];
#pragma unroll
        for (int j = 1; j < 8; ++j) m = fmaxf(m, x[i][j]);
        m = fmaxf(m, __shfl_xor(m, 1));
        m = fmaxf(m, __shfl_xor(m, 2));
        m = fmaxf(m, __shfl_xor(m, 4));
        m = fmaxf(m, __shfl_xor(m, 8));
        float s = 0.0f;
#pragma unroll
        for (int j = 0; j < 8; ++j) s += fexp2(x[i][j] - m);
        s += __shfl_xor(s, 1);
        s += __shfl_xor(s, 2);
        s += __shfl_xor(s, 4);
        s += __shfl_xor(s, 8);
        r[i] = m + flog2(fmaxf(s, FLT_MIN));
    }

    // ---- main loop: 20 x (col phase, row phase), then final col phase ----
#pragma unroll 1
    for (int it = 0; it < NITERS - 1; ++it) {
        // col phase: c[j] += log2( sum_i 2^(x - r_i - c_j) ), args <= 0
        {
            float sc[8];
#pragma unroll
            for (int j = 0; j < 8; ++j) sc[j] = 0.0f;
#pragma unroll
            for (int i = 0; i < 8; ++i) {
                const float ri = r[i];
#pragma unroll
                for (int j = 0; j < 8; ++j) sc[j] += fexp2(x[i][j] - ri - c[j]);
            }
#pragma unroll
            for (int j = 0; j < 8; ++j) {
                float s = sc[j];
                s += __shfl_xor(s, 16);
                s += __shfl_xor(s, 32);
                sc[j] = s;
            }
            if ((t & 63) < 16) {
#pragma unroll
                for (int j = 0; j < 8; ++j) lds[wv][((t & 15) << 3) + j] = sc[j];
            }
            __syncthreads();
#pragma unroll
            for (int j = 0; j < 8; ++j) {
                const int col = (cg << 3) + j;
                float tot = lds[0][col] + lds[1][col] + lds[2][col] + lds[3][col];
                c[j] += flog2(fmaxf(tot, FLT_MIN));
            }
            __syncthreads();
        }
        // row phase: r[i] += log2( sum_j 2^(x - c_j - r_i) ), args <= 0
#pragma unroll
        for (int i = 0; i < 8; ++i) {
            const float ri = r[i];
            float s = 0.0f;
#pragma unroll
            for (int j = 0; j < 8; ++j) s += fexp2(x[i][j] - c[j] - ri);
            s += __shfl_xor(s, 1);
            s += __shfl_xor(s, 2);
            s += __shfl_xor(s, 4);
            s += __shfl_xor(s, 8);
            r[i] = ri + flog2(fmaxf(s, FLT_MIN));
        }
    }

    // final col phase (21st)
    {
        float sc[8];
#pragma unroll
        for (int j = 0; j < 8; ++j) sc[j] = 0.0f;
#pragma unroll
        for (int i = 0; i < 8; ++i) {
            const float ri = r[i];
#pragma unroll
            for (int j = 0; j < 8; ++j) sc[j] += fexp2(x[i][j] - ri - c[j]);
        }
#pragma unroll
        for (int j = 0; j < 8; ++j) {
            float s = sc[j];
            s += __shfl_xor(s, 16);
            s += __shfl_xor(s, 32);
            sc[j] = s;
        }
        if ((t & 63) < 16) {
#pragma unroll
            for (int j = 0; j < 8; ++j) lds[wv][((t & 15) << 3) + j] = sc[j];
        }
        __syncthreads();
#pragma unroll
        for (int j = 0; j < 8; ++j) {
            const int col = (cg << 3) + j;
            float tot = lds[0][col] + lds[1][col] + lds[2][col] + lds[3][col];
            c[j] += flog2(fmaxf(tot, FLT_MIN));
        }
    }

    // ---- output: exp(la) = 2^(x - r_i - c_j) ----
#pragma unroll
    for (int i = 0; i < 8; ++i) {
        float4 a, b;
        a.x = fexp2(x[i][0] - r[i] - c[0]);
        a.y = fexp2(x[i][1] - r[i] - c[1]);
        a.z = fexp2(x[i][2] - r[i] - c[2]);
        a.w = fexp2(x[i][3] - r[i] - c[3]);
        b.x = fexp2(x[i][4] - r[i] - c[4]);
        b.y = fexp2(x[i][5] - r[i] - c[5]);
        b.z = fexp2(x[i][6] - r[i] - c[6]);
        b.w = fexp2(x[i][7] - r[i] - c[7]);
        *(float4*)(dst + i * 128)     = a;
        *(float4*)(dst + i * 128 + 4) = b;
    }
}

extern "C" void kernel_launch(void* const* d_in, const int* in_sizes, int n_in,
                              void* d_out, int out_size, void* d_ws, size_t ws_size,
                              hipStream_t stream) {
    (void)n_in; (void)d_ws; (void)ws_size; (void)out_size;
    const float* in  = (const float*)d_in[0];
    float*       out = (float*)d_out;
    const int n_mat = in_sizes[0] / (128 * 128);  // 4096
    sinkhorn_kernel<<<dim3(n_mat), dim3(256), 0, stream>>>(in, out);
}

// Round 2
// 185.654 us; speedup vs baseline: 2.5677x; 2.5677x over previous
//
#include <hip/hip_runtime.h>
#include <cfloat>

template<int CTRL>
__device__ __forceinline__ float dppmov(float v) {
    return __int_as_float(__builtin_amdgcn_mov_dpp(__float_as_int(v), CTRL, 0xF, 0xF, true));
}

// all-reduce sum/max across each 16-lane group, result in every lane (pure VALU, no LDS pipe)
__device__ __forceinline__ float sum16(float v) {
    v += dppmov<0xB1>(v);    // quad_perm [1,0,3,2]  : xor 1
    v += dppmov<0x4E>(v);    // quad_perm [2,3,0,1]  : xor 2
    v += dppmov<0x124>(v);   // row_ror:4
    v += dppmov<0x128>(v);   // row_ror:8
    return v;
}
__device__ __forceinline__ float max16(float v) {
    v = fmaxf(v, dppmov<0xB1>(v));
    v = fmaxf(v, dppmov<0x4E>(v));
    v = fmaxf(v, dppmov<0x124>(v));
    v = fmaxf(v, dppmov<0x128>(v));
    return v;
}

#define NIT 21
#define SMIN 1e-33f

// One 256-thread block per 128x128 matrix. Thread t owns an 8x8 tile:
// rows rg*8.., cols cg*8.. (rg=t>>4, cg=t&15). Linear-space Sinkhorn with
// fixed kernel K = 2^(x/T*log2e - rowmax) in registers; per-phase scale
// factors a_i (rows), b_j (cols) via FMA sums + v_rcp. No exp/log in the loop.
__global__ __launch_bounds__(256) void sinkhorn_kernel(const float* __restrict__ in,
                                                       float* __restrict__ out) {
    const int t  = threadIdx.x;
    const int rg = t >> 4;
    const int cg = t & 15;
    const int wv = t >> 6;
    const size_t base = (size_t)blockIdx.x * (128 * 128);
    const float* __restrict__ src = in  + base + ((size_t)rg << 10) + ((size_t)cg << 3);
    float*       __restrict__ dst = out + base + ((size_t)rg << 10) + ((size_t)cg << 3);

    const float SCALE = 36.067376022224085f;  // (1/0.04) * log2(e)

    float E[8][8];
#pragma unroll
    for (int i = 0; i < 8; ++i) {
        float4 a4 = *(const float4*)(src + (i << 7));
        float4 b4 = *(const float4*)(src + (i << 7) + 4);
        E[i][0] = a4.x * SCALE; E[i][1] = a4.y * SCALE;
        E[i][2] = a4.z * SCALE; E[i][3] = a4.w * SCALE;
        E[i][4] = b4.x * SCALE; E[i][5] = b4.y * SCALE;
        E[i][6] = b4.z * SCALE; E[i][7] = b4.w * SCALE;
    }

    float a[8], b[8];

    // ---- row phase 1 fused with exponentiation: E = 2^(x - rowmax), a_i = 1/rowsum ----
#pragma unroll
    for (int i = 0; i < 8; ++i) {
        float m = E[i][0];
#pragma unroll
        for (int j = 1; j < 8; ++j) m = fmaxf(m, E[i][j]);
        m = max16(m);
        float s = 0.f;
#pragma unroll
        for (int j = 0; j < 8; ++j) {
            E[i][j] = __builtin_amdgcn_exp2f(E[i][j] - m);
            s += E[i][j];
        }
        s = sum16(s);
        a[i] = __builtin_amdgcn_rcpf(s);   // s in [1,128], exact-safe
    }

    // cross-wave col partials, double-buffered; split-quad layout -> 2-way banks (free)
    __shared__ float4 part[2][4][32];
    int pb = 0;

#pragma unroll 1
    for (int it = 0; it < NIT; ++it) {
        // ---- col phase: b_j = 1 / sum_i E_ij * a_i ----
        float sc[8];
#pragma unroll
        for (int j = 0; j < 8; ++j) sc[j] = 0.f;
#pragma unroll
        for (int i = 0; i < 8; ++i) {
            const float ai = a[i];
#pragma unroll
            for (int j = 0; j < 8; ++j) sc[j] = fmaf(E[i][j], ai, sc[j]);
        }
#pragma unroll
        for (int j = 0; j < 8; ++j) {      // reduce over the 4 row-groups in this wave
            float s = sc[j];
            s += __shfl_xor(s, 16);
            s += __shfl_xor(s, 32);
            sc[j] = s;
        }
        if ((t & 63) < 16) {
            part[pb][wv][t & 15]        = make_float4(sc[0], sc[1], sc[2], sc[3]);
            part[pb][wv][16 + (t & 15)] = make_float4(sc[4], sc[5], sc[6], sc[7]);
        }
        __syncthreads();
        {
            float4 lo = part[pb][0][cg];
            float4 hi = part[pb][0][16 + cg];
#pragma unroll
            for (int w = 1; w < 4; ++w) {
                float4 l2 = part[pb][w][cg];
                float4 h2 = part[pb][w][16 + cg];
                lo.x += l2.x; lo.y += l2.y; lo.z += l2.z; lo.w += l2.w;
                hi.x += h2.x; hi.y += h2.y; hi.z += h2.z; hi.w += h2.w;
            }
            b[0] = __builtin_amdgcn_rcpf(fmaxf(lo.x, SMIN));
            b[1] = __builtin_amdgcn_rcpf(fmaxf(lo.y, SMIN));
            b[2] = __builtin_amdgcn_rcpf(fmaxf(lo.z, SMIN));
            b[3] = __builtin_amdgcn_rcpf(fmaxf(lo.w, SMIN));
            b[4] = __builtin_amdgcn_rcpf(fmaxf(hi.x, SMIN));
            b[5] = __builtin_amdgcn_rcpf(fmaxf(hi.y, SMIN));
            b[6] = __builtin_amdgcn_rcpf(fmaxf(hi.z, SMIN));
            b[7] = __builtin_amdgcn_rcpf(fmaxf(hi.w, SMIN));
        }
        pb ^= 1;

        // ---- row phase: a_i = 1 / sum_j E_ij * b_j  (skipped after the 21st col) ----
        if (it < NIT - 1) {
#pragma unroll
            for (int i = 0; i < 8; ++i) {
                float s = 0.f;
#pragma unroll
                for (int j = 0; j < 8; ++j) s = fmaf(E[i][j], b[j], s);
                s = sum16(s);
                a[i] = __builtin_amdgcn_rcpf(fmaxf(s, SMIN));
            }
        }
    }

    // ---- epilogue: out = E * a_i * b_j ----
#pragma unroll
    for (int i = 0; i < 8; ++i) {
        const float ai = a[i];
        float4 o0, o1;
        o0.x = E[i][0] * ai * b[0];
        o0.y = E[i][1] * ai * b[1];
        o0.z = E[i][2] * ai * b[2];
        o0.w = E[i][3] * ai * b[3];
        o1.x = E[i][4] * ai * b[4];
        o1.y = E[i][5] * ai * b[5];
        o1.z = E[i][6] * ai * b[6];
        o1.w = E[i][7] * ai * b[7];
        *(float4*)(dst + (i << 7))     = o0;
        *(float4*)(dst + (i << 7) + 4) = o1;
    }
}

extern "C" void kernel_launch(void* const* d_in, const int* in_sizes, int n_in,
                              void* d_out, int out_size, void* d_ws, size_t ws_size,
                              hipStream_t stream) {
    (void)n_in; (void)d_ws; (void)ws_size; (void)out_size;
    const float* in  = (const float*)d_in[0];
    float*       out = (float*)d_out;
    const int n_mat = in_sizes[0] / (128 * 128);  // 4096
    sinkhorn_kernel<<<dim3(n_mat), dim3(256), 0, stream>>>(in, out);
}